// Round 8
// baseline (390.011 us; speedup 1.0000x reference)
//
#include <hip/hip_runtime.h>

typedef unsigned short ushort_t;
typedef unsigned int uint_t;
typedef __bf16 bf16x8 __attribute__((ext_vector_type(8)));
typedef float f32x4 __attribute__((ext_vector_type(4)));

#define B_ROWS 65536

// Tile geometry: one MFMA tile = 16 rows x 32 k of bf16 = 1024 B = 512 ushorts.
// Unit l (0..63) within a tile <-> (row = l&15, k = (l>>4)*8 .. +8).
#define KT1 12    // x' k-tiles   (K 376 -> 384)
#define NT1 30    // K1 n-tiles   (N 400 -> 480)
#define KTC1 15   // h1' k-tiles  (480/32)
#define KI2 13    // K2 k-iters   (K 400 -> 416)
#define NT2 20    // K2 n-tiles   (N 320)
#define KTC2 10   // h2' k-tiles  (320/32)
#define KI3 10    // K3 k-iters   (320/32)
#define NT3 40    // K3 n-tiles   (N 560 -> 640)

#define SZ1 (NT1 * KT1 * 512)
#define SZ2 (NT2 * KI2 * 512)
#define SZ3 (NT3 * KI3 * 512)

__device__ inline float bf2f(ushort_t u) {
    union { uint_t i; float f; } x; x.i = ((uint_t)u) << 16; return x.f;
}
__device__ inline ushort_t f2bf(float f) {
    uint_t u = __float_as_uint(f);
    return (ushort_t)((u + 0x7FFFu + ((u >> 16) & 1u)) >> 16);
}
__device__ inline uint_t pack2(float a, float b) {
    return (uint_t)f2bf(a) | ((uint_t)f2bf(b) << 16);
}
__device__ inline float fast_tanh(float x) {
    float e = __expf(2.f * x);
    return 1.f - 2.f / (e + 1.f);
}
// async global->LDS, 16 B per lane; LDS dest = wave-uniform base + lane*16
__device__ inline void gl2lds16(const ushort_t* g, ushort_t* l) {
    __builtin_amdgcn_global_load_lds(
        (const __attribute__((address_space(1))) uint_t*)g,
        (__attribute__((address_space(3))) uint_t*)l, 16, 0, 0);
}

// ---------------------------------------------------------------------------
// pack_kernel: fp32 weights -> MFMA-tile-order bf16 + zero-padded fp32 biases.
//  head cols: [0:17) mu, [17:34) lv, [34:289) u, [289:544) w, [544:559) b
// ---------------------------------------------------------------------------
__global__ void pack_kernel(const float* __restrict__ W1, const float* __restrict__ W2,
                            const float* __restrict__ Wmu, const float* __restrict__ Wlv,
                            const float* __restrict__ Wu, const float* __restrict__ Ww,
                            const float* __restrict__ Wb,
                            const float* __restrict__ b1, const float* __restrict__ b2,
                            const float* __restrict__ bmu, const float* __restrict__ blv,
                            const float* __restrict__ bu, const float* __restrict__ bw,
                            const float* __restrict__ bb,
                            ushort_t* __restrict__ W1t, ushort_t* __restrict__ W2t,
                            ushort_t* __restrict__ Wht,
                            float* __restrict__ b1p, float* __restrict__ b2p,
                            float* __restrict__ bHp)
{
    int i = blockIdx.x * 256 + threadIdx.x;
    if (i < SZ1) {
        int t = i >> 9, pos = i & 511;
        int l = pos >> 3, j = pos & 7;
        int n = (t / KT1) * 16 + (l & 15);
        int k = (t % KT1) * 32 + (l >> 4) * 8 + j;
        W1t[i] = (n < 400 && k < 376) ? f2bf(W1[k * 400 + n]) : (ushort_t)0;
    } else if (i < SZ1 + SZ2) {
        int i2 = i - SZ1;
        int t = i2 >> 9, pos = i2 & 511;
        int l = pos >> 3, j = pos & 7;
        int n = (t / KI2) * 16 + (l & 15);
        int k = (t % KI2) * 32 + (l >> 4) * 8 + j;
        W2t[i2] = (n < 300 && k < 400) ? f2bf(W2[k * 300 + n]) : (ushort_t)0;
    } else if (i < SZ1 + SZ2 + SZ3) {
        int i3 = i - SZ1 - SZ2;
        int t = i3 >> 9, pos = i3 & 511;
        int l = pos >> 3, j = pos & 7;
        int n = (t / KI3) * 16 + (l & 15);
        int k = (t % KI3) * 32 + (l >> 4) * 8 + j;
        float v = 0.f;
        if (k < 300) {
            if      (n < 17)  v = Wmu[k * 17 + n];
            else if (n < 34)  v = Wlv[k * 17 + (n - 17)];
            else if (n < 289) v = Wu[k * 255 + (n - 34)];
            else if (n < 544) v = Ww[k * 255 + (n - 289)];
            else if (n < 559) v = Wb[k * 15 + (n - 544)];
        }
        Wht[i3] = f2bf(v);
    } else {
        int j = i - SZ1 - SZ2 - SZ3;
        if (j < 480) {
            b1p[j] = (j < 400) ? b1[j] : 0.f;
        } else if (j < 800) {
            int n = j - 480;
            b2p[n] = (n < 300) ? b2[n] : 0.f;
        } else if (j < 1440) {
            int n = j - 800;
            float v = 0.f;
            if      (n < 17)  v = bmu[n];
            else if (n < 34)  v = blv[n - 17];
            else if (n < 289) v = bu[n - 34];
            else if (n < 544) v = bw[n - 289];
            else if (n < 559) v = bb[n - 544];
            bHp[n] = v;
        }
    }
}

// ---------------------------------------------------------------------------
// cvt_kernel: x fp32 row-major -> x' bf16 tile-order. One thread per 16-B unit.
// ---------------------------------------------------------------------------
__global__ __launch_bounds__(256)
void cvt_kernel(const float* __restrict__ x, ushort_t* __restrict__ xt, int nUnits)
{
    int U = blockIdx.x * 256 + threadIdx.x;
    if (U >= nUnits) return;
    int t = U >> 6, l = U & 63;
    int rowblk = t / KT1, kblk = t - rowblk * KT1;
    long row = (long)rowblk * 16 + (l & 15);
    int k0 = kblk * 32 + (l >> 4) * 8;
    uint4 o = {0u, 0u, 0u, 0u};
    if (k0 + 8 <= 376) {
        const float4* p = reinterpret_cast<const float4*>(x + row * 376 + k0);
        float4 v0 = p[0], v1 = p[1];
        o.x = pack2(v0.x, v0.y); o.y = pack2(v0.z, v0.w);
        o.z = pack2(v1.x, v1.y); o.w = pack2(v1.z, v1.w);
    }
    reinterpret_cast<uint4*>(xt)[U] = o;
}

// ---------------------------------------------------------------------------
// gemm_tile: C = act(A @ B^T + bias). A, B in MFMA-tile order.
// OMODE 0: C in tile order (stride kTC ktiles) — feeds next GEMM.
// OMODE 1: C column-blocked transpose [rowgroup of 128][col<560][row in group]
//          — feeds flow_kernel with perfectly coalesced reads.
// BM=128 (8 rowtiles), BN=160 (10 ntiles), BK=32; 256 thr = 4 waves.
// ---------------------------------------------------------------------------
template<bool RELU, int OMODE>
__global__ __launch_bounds__(256)
void gemm_tile(const ushort_t* __restrict__ A, const ushort_t* __restrict__ Bt,
               const float* __restrict__ bias, ushort_t* __restrict__ C,
               int kTA, int kIters, int kTC)
{
    __shared__ ushort_t As[8 * 512];
    __shared__ ushort_t Bs[10 * 512];
    const int tid = threadIdx.x;
    const int lane = tid & 63, wv = tid >> 6;
    const int q = lane >> 4, l16 = lane & 15;
    const int nb0 = blockIdx.x * 10;
    const int rowblk0 = blockIdx.y * 8;

    f32x4 acc[2][10];
    #pragma unroll
    for (int r = 0; r < 2; ++r)
        #pragma unroll
        for (int c = 0; c < 10; ++c)
            acc[r][c] = (f32x4){0.f, 0.f, 0.f, 0.f};

    for (int kt = 0; kt < kIters; ++kt) {
        #pragma unroll
        for (int i = 0; i < 2; ++i) {
            int t = wv * 2 + i;
            gl2lds16(A + (((size_t)(rowblk0 + t) * kTA + kt) << 9) + lane * 8,
                     &As[t << 9]);
        }
        #pragma unroll
        for (int t2 = 0; t2 < 3; ++t2) {
            int t = wv + t2 * 4;
            if (t < 10)
                gl2lds16(Bt + (((size_t)(nb0 + t) * kIters + kt) << 9) + lane * 8,
                         &Bs[t << 9]);
        }
        __syncthreads();

        bf16x8 a0 = __builtin_bit_cast(bf16x8,
            *reinterpret_cast<const uint4*>(&As[((wv * 2 + 0) << 9) + lane * 8]));
        bf16x8 a1 = __builtin_bit_cast(bf16x8,
            *reinterpret_cast<const uint4*>(&As[((wv * 2 + 1) << 9) + lane * 8]));
        #pragma unroll
        for (int c = 0; c < 10; ++c) {
            bf16x8 b = __builtin_bit_cast(bf16x8,
                *reinterpret_cast<const uint4*>(&Bs[(c << 9) + lane * 8]));
            acc[0][c] = __builtin_amdgcn_mfma_f32_16x16x32_bf16(a0, b, acc[0][c], 0, 0, 0);
            acc[1][c] = __builtin_amdgcn_mfma_f32_16x16x32_bf16(a1, b, acc[1][c], 0, 0, 0);
        }
        __syncthreads();
    }

    // epilogue; C/D frag: col = l16, row = q*4+reg
    #pragma unroll
    for (int r = 0; r < 2; ++r) {
        int rowblk = rowblk0 + wv * 2 + r;
        #pragma unroll
        for (int c = 0; c < 10; ++c) {
            int n = (nb0 + c) * 16 + l16;
            float bv = bias[n];
            #pragma unroll
            for (int reg = 0; reg < 4; ++reg) {
                float v = acc[r][c][reg] + bv;
                if (RELU) v = fmaxf(v, 0.f);
                int mrow = q * 4 + reg;
                if (OMODE == 0) {
                    size_t off = (((size_t)rowblk * kTC + (n >> 5)) << 9)
                               + (size_t)(((n >> 3) & 3) * 16 + mrow) * 8 + (n & 7);
                    C[off] = f2bf(v);
                } else {
                    if (n < 560) {
                        size_t off = (size_t)(rowblk >> 3) * (560 * 128)
                                   + (size_t)n * 128 + ((rowblk & 7) * 16 + mrow);
                        C[off] = f2bf(v);
                    }
                }
            }
        }
    }
}

// ---------------------------------------------------------------------------
// flow_kernel v3: one THREAD per row, NO LDS, NO barriers. headsT is
// column-blocked: h[sblk][col][row&127] -> read of col j = h[j*128 + tid],
// perfectly coalesced across the wave. Fully unrolled k-loop gives the ILP
// to hide latency at low occupancy.
// ---------------------------------------------------------------------------
__global__ __launch_bounds__(128)
void flow_kernel(const ushort_t* __restrict__ hT, const float* __restrict__ eps,
                 float* __restrict__ out, int rowBase, int B)
{
    const int tid = threadIdx.x;
    const ushort_t* h = hT + (size_t)blockIdx.x * (560 * 128) + tid;
    const long g = rowBase + (long)blockIdx.x * 128 + tid;

    float z[17];
    float lp = 0.f;
    #pragma unroll
    for (int i = 0; i < 17; ++i) {
        float mu = fast_tanh(bf2f(h[i * 128]));
        float lv = fast_tanh(bf2f(h[(17 + i) * 128]));
        float ep = eps[g * 17 + i];
        z[i] = mu + __expf(lv) * ep;
        lp += -0.5f * ep * ep - lv - 0.918938533f;
    }

    float ldj = 0.f;
    #pragma unroll
    for (int k = 0; k < 15; ++k) {
        float u[17], w[17];
        #pragma unroll
        for (int i = 0; i < 17; ++i) {
            u[i] = bf2f(h[(34 + k * 17 + i) * 128]);
            w[i] = bf2f(h[(289 + k * 17 + i) * 128]);
        }
        float bk = bf2f(h[(544 + k) * 128]);
        float uw = 0.f, w2 = 0.f, wz = 0.f;
        #pragma unroll
        for (int i = 0; i < 17; ++i) {
            uw += w[i] * u[i];
            w2 += w[i] * w[i];
            wz += w[i] * z[i];
        }
        float sp = (uw > 15.f) ? uw : __logf(1.f + __expf(uw));
        float m = sp - 1.f;                          // -1 + softplus(w.u)
        float coef = (m - uw) / fmaxf(w2, 1e-20f);
        float t = fast_tanh(wz + bk);
        #pragma unroll
        for (int i = 0; i < 17; ++i)
            z[i] += (u[i] + coef * w[i]) * t;
        float psi = m * (1.f - t * t);               // psi^T u_hat == m analytically
        ldj += __logf(fmaxf(fabsf(1.f + psi), 1e-30f));
    }

    #pragma unroll
    for (int i = 0; i < 17; ++i) out[g * 17 + i] = z[i];
    float lpf = lp - ldj;
    out[(long)B * 17 + g] = __expf(lpf);
    out[(long)B * 18 + g] = lpf;
}

// ---------------------------------------------------------------------------
extern "C" void kernel_launch(void* const* d_in, const int* in_sizes, int n_in,
                              void* d_out, int out_size, void* d_ws, size_t ws_size,
                              hipStream_t stream)
{
    const float* x   = (const float*)d_in[0];
    const float* eps = (const float*)d_in[1];
    float* out = (float*)d_out;

    // ws layout per chunk of Mc rows:
    //   regA (Mc*384 us): x' tiled  -> h2' tiled (Mc*320)
    //   regB (Mc*560 us): h1' tiled (Mc*480) -> headsT col-blocked (Mc*560)
    //   weights: W1t | W2t | Wht | b1p(480 f32) | b2p(320) | bHp(640)
    const size_t wUS = (size_t)SZ1 + SZ2 + SZ3;
    const size_t fixedBytes = wUS * 2 + (480 + 320 + 640) * 4;
    int Mc = 2048;
    {
        const int cand[6] = {65536, 32768, 16384, 8192, 4096, 2048};
        for (int i = 0; i < 6; ++i) {
            size_t req = (size_t)cand[i] * 1888 + fixedBytes;
            if (req <= ws_size) { Mc = cand[i]; break; }
        }
    }

    ushort_t* regA = (ushort_t*)d_ws;
    ushort_t* regB = regA + (size_t)Mc * 384;
    ushort_t* W1t = regB + (size_t)Mc * 560;
    ushort_t* W2t = W1t + SZ1;
    ushort_t* Wht = W2t + SZ2;
    float* b1p = (float*)(Wht + SZ3);
    float* b2p = b1p + 480;
    float* bHp = b2p + 320;

    const int packN = SZ1 + SZ2 + SZ3 + 1440;
    pack_kernel<<<(packN + 255) / 256, 256, 0, stream>>>(
        (const float*)d_in[2],  (const float*)d_in[4],
        (const float*)d_in[6],  (const float*)d_in[8],
        (const float*)d_in[10], (const float*)d_in[12], (const float*)d_in[14],
        (const float*)d_in[3],  (const float*)d_in[5],
        (const float*)d_in[7],  (const float*)d_in[9],
        (const float*)d_in[11], (const float*)d_in[13], (const float*)d_in[15],
        W1t, W2t, Wht, b1p, b2p, bHp);

    const int nChunks = B_ROWS / Mc;
    const int nUnits = Mc * 48;
    for (int c = 0; c < nChunks; ++c) {
        const float* xc = x + (size_t)c * Mc * 376;
        // C0: x -> x' tiled (regA)
        cvt_kernel<<<(nUnits + 255) / 256, 256, 0, stream>>>(xc, regA, nUnits);
        // K1: h1' = relu(x' @ W1^T + b1) -> regB tiled (stride 15)
        gemm_tile<true, 0><<<dim3(3, Mc / 128), 256, 0, stream>>>(
            regA, W1t, b1p, regB, KT1, KT1, KTC1);
        // K2: h2' = relu(h1' @ W2^T + b2) -> regA tiled (stride 10)
        gemm_tile<true, 0><<<dim3(2, Mc / 128), 256, 0, stream>>>(
            regB, W2t, b2p, regA, KTC1, KI2, KTC2);
        // K3: headsT = h2' @ Wh^T + bH -> regB col-blocked transpose
        gemm_tile<false, 1><<<dim3(4, Mc / 128), 256, 0, stream>>>(
            regA, Wht, bHp, regB, KTC2, KI3, 0);
        // K4: planar flow + log-prob (coalesced, no LDS)
        flow_kernel<<<Mc / 128, 128, 0, stream>>>(regB, eps + (size_t)c * Mc * 17,
                                                  out, c * Mc, B_ROWS);
    }
}